// Round 7
// baseline (335.618 us; speedup 1.0000x reference)
//
#include <hip/hip_runtime.h>
#include <stdint.h>

#define T_LEN 200
#define B_SZ  1024
#define D_DIM 128
#define LOG2E 1.44269504088896340736f

typedef __bf16 bf16_t;
typedef __bf16 bf16x8 __attribute__((ext_vector_type(8)));
typedef float  f32x4  __attribute__((ext_vector_type(4)));

union BF8 { bf16x8 v; bf16_t e[8]; };

// RNE fp32->bf16 pack of two values into one dword
__device__ inline uint32_t pk_bf16(float a, float b) {
  uint32_t ua = __float_as_uint(a), ub = __float_as_uint(b);
  ua += 0x7fffu + ((ua >> 16) & 1u);
  ub += 0x7fffu + ((ub >> 16) & 1u);
  return (ua >> 16) | (ub & 0xffff0000u);
}
__device__ inline float rcp_f(float x) { return __builtin_amdgcn_rcpf(x); }

// LDS-only barrier: wait LDS ops, leave global loads (vmcnt) in flight.
#define BAR_LDS() asm volatile("s_waitcnt lgkmcnt(0)\n\ts_barrier" ::: "memory")

// ---------------------------------------------------------------------------
// Fused AUGRU scan — 4 waves x 2 col-slices per wave (cuts per-CU LDS frag
// reads 64->32 b128/step and barrier participants 8->4).
// 64 blocks x 256 threads; block bb owns batch rows [16*bb, 16*bb+16);
// wave w owns cols [32w, 32w+32) as slices col0=32w+lm, col1=col0+16.
// LDS layouts (halfword index):
//   xb: slot(row,k) = (k>>3)*128 + row*8 + (k&7)
//       staging: thread tid writes 16B at halfword (tid>>4)*128+(tid&15)*8
//       (lane-contiguous b128, conflict-free); frag read = 16B at 16*l.
//   sb: slot(row,k) = (k>>3)*128 + (row^(2*((k>>3)&1)))*8 + (k&7)
//       reader frag = 8*(l^(2*(lg&1))); writer wbase + j*256 + 8*(i^psi).
// ---------------------------------------------------------------------------
__global__ __launch_bounds__(256, 1) void augru_fused(
    const float* __restrict__ x,
    const float* __restrict__ state,
    const float* __restrict__ att,
    const float* __restrict__ mask,
    const float* __restrict__ Wau, const float* __restrict__ bau,
    const float* __restrict__ Wbu,
    const float* __restrict__ War, const float* __restrict__ bar,
    const float* __restrict__ Wbr,
    const float* __restrict__ Wac, const float* __restrict__ bac,
    const float* __restrict__ Wbc,
    float* __restrict__ out)
{
  __shared__ bf16_t xb[2][2048];         // x tiles ping-pong (bf16)
  __shared__ bf16_t sb[2][2048];         // state ping-pong (bf16, swizzled)
  __shared__ float  am_lds[T_LEN * 16];  // att*mask fused, [t][row]

  const int tid = threadIdx.x;
  const int w  = tid >> 6;               // wave 0..3
  const int l  = tid & 63;
  const int lm = l & 15;
  const int lg = l >> 4;
  const int bb = blockIdx.x;
  const int R0 = bb * 16;
  const int col0 = w * 32 + lm;          // slice 0 column
  // slice 1 column = col0 + 16

  // --- weight B-fragments: 6 matrices x 2 slices x 4 kk (192 VGPRs)
  BF8 xu[2][4], xr[2][4], xc[2][4];
  BF8 su[2][4], sr[2][4], sc[2][4];
  float b_u[2], b_r[2], b_c[2];
#pragma unroll
  for (int j = 0; j < 2; ++j) {
    const int cj = col0 + 16 * j;
#pragma unroll
    for (int kk = 0; kk < 4; ++kk) {
#pragma unroll
      for (int e = 0; e < 8; ++e) {
        int k = kk * 32 + lg * 8 + e;
        xu[j][kk].e[e] = (bf16_t)(Wau[k * 128 + cj] * LOG2E);
        xr[j][kk].e[e] = (bf16_t)(War[k * 128 + cj] * LOG2E);
        xc[j][kk].e[e] = (bf16_t)(Wac[k * 128 + cj] * (2.0f * LOG2E));
        su[j][kk].e[e] = (bf16_t)(Wbu[k * 128 + cj] * LOG2E);
        sr[j][kk].e[e] = (bf16_t)(Wbr[k * 128 + cj] * LOG2E);
        sc[j][kk].e[e] = (bf16_t)(Wbc[k * 128 + cj] * (2.0f * LOG2E));
      }
    }
    b_u[j] = bau[cj] * LOG2E;
    b_r[j] = bar[cj] * LOG2E;
    b_c[j] = bac[cj] * (2.0f * LOG2E);
  }

  // --- att*mask preload
  for (int idx = tid; idx < T_LEN * 16; idx += 256) {
    int t = idx >> 4, row = idx & 15;
    am_lds[idx] = att[t * B_SZ + R0 + row] * mask[(R0 + row) * T_LEN + t];
  }

  // --- fp32 state in registers: lane owns (row = lg*4+i, col_j)
  float sreg[2][4];
#pragma unroll
  for (int j = 0; j < 2; ++j)
#pragma unroll
    for (int i = 0; i < 4; ++i)
      sreg[j][i] = state[(R0 + lg * 4 + i) * 128 + col0 + 16 * j];

  // state bf16 into sb[0], swizzled
  for (int idx = tid; idx < 2048; idx += 256) {
    int row = idx >> 7, k = idx & 127;
    sb[0][(k >> 3) * 128 + (row ^ (2 * ((k >> 3) & 1))) * 8 + (k & 7)] =
        (bf16_t)state[(R0 + row) * 128 + k];
  }

  // --- x staging: thread tid stages row=tid&15, 8-float chunk m=tid>>4
  const int srow = tid & 15;
  const int sm   = tid >> 4;                       // 0..15
  const int stg_pos = sm * 128 + srow * 8;         // halfword, 16B aligned
  const float* xrow = x + (size_t)(R0 + srow) * 128 + sm * 8;
  const size_t xstep = (size_t)B_SZ * 128;

  auto stage = [&](float4 a, float4 b, int buf) {
    uint4 p;
    p.x = pk_bf16(a.x, a.y); p.y = pk_bf16(a.z, a.w);
    p.z = pk_bf16(b.x, b.y); p.w = pk_bf16(b.z, b.w);
    *(uint4*)&xb[buf][stg_pos] = p;
  };

  // prologue: stage x(0)->xb[0], x(1)->xb[1]; register-prefetch x(2..4)
  {
    float4 a0 = *(const float4*)(xrow);
    float4 b0 = *(const float4*)(xrow + 4);
    float4 a1 = *(const float4*)(xrow + xstep);
    float4 b1 = *(const float4*)(xrow + xstep + 4);
    stage(a0, b0, 0);
    stage(a1, b1, 1);
  }
  float4 xqa0 = *(const float4*)(xrow + 2 * xstep);
  float4 xqb0 = *(const float4*)(xrow + 2 * xstep + 4);
  float4 xqa1 = *(const float4*)(xrow + 3 * xstep);
  float4 xqb1 = *(const float4*)(xrow + 3 * xstep + 4);
  float4 xqa2 = *(const float4*)(xrow + 4 * xstep);
  float4 xqb2 = *(const float4*)(xrow + 4 * xstep + 4);

  __syncthreads();   // full drain once

  // x-gates(0) from xb[0]
  f32x4 gU[2], gR[2], gC[2];
#pragma unroll
  for (int j = 0; j < 2; ++j) {
    gU[j] = f32x4{b_u[j], b_u[j], b_u[j], b_u[j]};
    gR[j] = f32x4{b_r[j], b_r[j], b_r[j], b_r[j]};
    gC[j] = f32x4{b_c[j], b_c[j], b_c[j], b_c[j]};
  }
  {
    bf16x8 ax[4];
#pragma unroll
    for (int kk = 0; kk < 4; ++kk)
      ax[kk] = *(const bf16x8*)&xb[0][kk * 512 + 8 * l];
#pragma unroll
    for (int kk = 0; kk < 4; ++kk)
#pragma unroll
      for (int j = 0; j < 2; ++j) {
        gU[j] = __builtin_amdgcn_mfma_f32_16x16x32_bf16(ax[kk], xu[j][kk].v, gU[j], 0, 0, 0);
        gR[j] = __builtin_amdgcn_mfma_f32_16x16x32_bf16(ax[kk], xr[j][kk].v, gR[j], 0, 0, 0);
        gC[j] = __builtin_amdgcn_mfma_f32_16x16x32_bf16(ax[kk], xc[j][kk].v, gC[j], 0, 0, 0);
      }
  }
  union F4 { float4 v; float e[4]; } amv;
  amv.v = *(const float4*)&am_lds[lg * 4];   // am(0)

  const int lx8   = 8 * (l ^ (2 * (lg & 1)));
  const int psi   = 2 * ((col0 >> 3) & 1);   // same for both slices
  const int wbase = (col0 >> 3) * 128 + lg * 32 + (col0 & 7);

  BAR_LDS();   // protect xb[0] (read above) before step 0 re-stages it

  auto step = [&](int t) {
    const int rp = t & 1;

    // 1) s(t) fragments — first on the LDS pipe
    bf16x8 as_[4];
#pragma unroll
    for (int kk = 0; kk < 4; ++kk)
      as_[kk] = *(const bf16x8*)&sb[rp][kk * 512 + lx8];

    // 2) state-side MFMAs (C-init = pipelined x-gates for t)
    f32x4 aU[2] = {gU[0], gU[1]};
    f32x4 aR[2] = {gR[0], gR[1]};
    f32x4 bC[2] = {f32x4{0,0,0,0}, f32x4{0,0,0,0}};
#pragma unroll
    for (int kk = 0; kk < 4; ++kk)
#pragma unroll
      for (int j = 0; j < 2; ++j) {
        aU[j] = __builtin_amdgcn_mfma_f32_16x16x32_bf16(as_[kk], su[j][kk].v, aU[j], 0, 0, 0);
        aR[j] = __builtin_amdgcn_mfma_f32_16x16x32_bf16(as_[kk], sr[j][kk].v, aR[j], 0, 0, 0);
        bC[j] = __builtin_amdgcn_mfma_f32_16x16x32_bf16(as_[kk], sc[j][kk].v, bC[j], 0, 0, 0);
      }

    // 3) x(t+1) fragments + x-side MFMAs (independent — fill s-chain latency)
    bf16x8 ax[4];
#pragma unroll
    for (int kk = 0; kk < 4; ++kk)
      ax[kk] = *(const bf16x8*)&xb[rp ^ 1][kk * 512 + 8 * l];

    f32x4 nU[2], nR[2], nC[2];
#pragma unroll
    for (int j = 0; j < 2; ++j) {
      nU[j] = f32x4{b_u[j], b_u[j], b_u[j], b_u[j]};
      nR[j] = f32x4{b_r[j], b_r[j], b_r[j], b_r[j]};
      nC[j] = f32x4{b_c[j], b_c[j], b_c[j], b_c[j]};
    }
#pragma unroll
    for (int kk = 0; kk < 4; ++kk)
#pragma unroll
      for (int j = 0; j < 2; ++j) {
        nU[j] = __builtin_amdgcn_mfma_f32_16x16x32_bf16(ax[kk], xu[j][kk].v, nU[j], 0, 0, 0);
        nR[j] = __builtin_amdgcn_mfma_f32_16x16x32_bf16(ax[kk], xr[j][kk].v, nR[j], 0, 0, 0);
        nC[j] = __builtin_amdgcn_mfma_f32_16x16x32_bf16(ax[kk], xc[j][kk].v, nC[j], 0, 0, 0);
      }

    // 4) epilogue + state write
    bf16_t* wbuf = sb[rp ^ 1];
#pragma unroll
    for (int j = 0; j < 2; ++j)
#pragma unroll
      for (int i = 0; i < 4; ++i) {
        float u  = rcp_f(1.0f + __builtin_amdgcn_exp2f(-aU[j][i]));
        float r  = rcp_f(1.0f + __builtin_amdgcn_exp2f(-aR[j][i]));
        float wc = fmaf(r, bC[j][i], gC[j][i]);
        float cg = fmaf(-2.0f, rcp_f(__builtin_amdgcn_exp2f(wc) + 1.0f), 1.0f);
        float sf = fmaf(amv.e[i] * u, cg - sreg[j][i], sreg[j][i]);
        sreg[j][i] = sf;
        wbuf[wbase + j * 256 + 8 * (i ^ psi)] = (bf16_t)sf;
      }

    // 5) stage x(t+2) into xb[rp]; rotate prefetch; issue load x(t+5)
    stage(xqa0, xqb0, rp);
    xqa0 = xqa1; xqb0 = xqb1;
    xqa1 = xqa2; xqb1 = xqb2;
    int tl = t + 5; if (tl > T_LEN - 1) tl = T_LEN - 1;
    xqa2 = *(const float4*)(xrow + (size_t)tl * xstep);
    xqb2 = *(const float4*)(xrow + (size_t)tl * xstep + 4);

    // 6) rotate gates; prefetch am(t+1)
#pragma unroll
    for (int j = 0; j < 2; ++j) { gU[j] = nU[j]; gR[j] = nR[j]; gC[j] = nC[j]; }
    int ta = t + 1; if (ta > T_LEN - 1) ta = T_LEN - 1;
    amv.v = *(const float4*)&am_lds[ta * 16 + lg * 4];

    BAR_LDS();
  };

#pragma unroll 1
  for (int t = 0; t < T_LEN; t += 2) {
    step(t);
    step(t + 1);
  }

#pragma unroll
  for (int j = 0; j < 2; ++j)
#pragma unroll
    for (int i = 0; i < 4; ++i)
      out[(R0 + lg * 4 + i) * 128 + col0 + 16 * j] = sreg[j][i];
}

// ---------------------------------------------------------------------------
extern "C" void kernel_launch(void* const* d_in, const int* in_sizes, int n_in,
                              void* d_out, int out_size, void* d_ws, size_t ws_size,
                              hipStream_t stream)
{
  const float* x    = (const float*)d_in[0];
  const float* st   = (const float*)d_in[1];
  const float* att  = (const float*)d_in[2];
  const float* mask = (const float*)d_in[3];
  // d_in[4] = max_len (unused; shapes hard-coded)
  const float* Wau  = (const float*)d_in[5];
  const float* bau  = (const float*)d_in[6];
  const float* Wbu  = (const float*)d_in[7];
  const float* War  = (const float*)d_in[8];
  const float* bar  = (const float*)d_in[9];
  const float* Wbr  = (const float*)d_in[10];
  const float* Wac  = (const float*)d_in[11];
  const float* bac  = (const float*)d_in[12];
  const float* Wbc  = (const float*)d_in[13];

  (void)d_ws; (void)ws_size;

  augru_fused<<<dim3(64), dim3(256), 0, stream>>>(
      x, st, att, mask, Wau, bau, Wbu, War, bar, Wbr, Wac, bac, Wbc,
      (float*)d_out);
}